// Round 7
// baseline (171.116 us; speedup 1.0000x reference)
//
#include <hip/hip_runtime.h>
#include <hip/hip_bf16.h>

typedef __bf16 bf16x8 __attribute__((ext_vector_type(8)));
typedef __bf16 bf16x4 __attribute__((ext_vector_type(4)));
typedef float  f32x4  __attribute__((ext_vector_type(4)));

#define HL   50     // history length
#define DD   64     // embed dim
#define MR   64     // padded M rows (50 live + 14 garbage)
#define MT   4      // M tiles
#define XSS  136    // xs row stride bf16

// ws layout: [0, 32768): 256 fragment-sets (fid = quad*64+col), each 64 bf16 =
//   { b1f[0..3] | b1u[0..1] | b2f[0..1] } x 8 bf16, exact mfma B-frag order.
// [32768, 33536): f32 scalars { w3[64] | b1[64] | b2[64] }.
__global__ __launch_bounds__(256) void va_prep_kernel(
    const float* __restrict__ W1, const float* __restrict__ W2,
    const float* __restrict__ w3, const float* __restrict__ b1,
    const float* __restrict__ b2,
    __bf16* __restrict__ wf, float* __restrict__ wsc)
{
    const int tid  = threadIdx.x;
    const int quad = tid >> 6;
    const int col  = tid & 63;
    __bf16* dst = wf + tid * 64;
    #pragma unroll
    for (int t = 0; t < 4; ++t)
        #pragma unroll
        for (int j = 0; j < 8; ++j) {
            int keff = t * 32 + quad * 8 + j;
            int krow = (keff < 64) ? keff : keff + 64;
            dst[t * 8 + j] = (__bf16)W1[krow * 64 + col];
        }
    #pragma unroll
    for (int t = 0; t < 2; ++t)
        #pragma unroll
        for (int j = 0; j < 8; ++j) {
            dst[32 + t * 8 + j] = (__bf16)W1[(64 + t * 32 + quad * 8 + j) * 64 + col];
            dst[48 + t * 8 + j] = (__bf16)W2[(t * 32 + quad * 8 + j) * 64 + col];
        }
    if (tid < 64) {
        wsc[tid]       = w3[tid];
        wsc[64 + tid]  = b1[tid];
        wsc[128 + tid] = b2[tid];
    }
}

// One node per block, 8192 blocks. LDS 18432 B -> 8 blocks/CU; VGPR capped at
// 64 via launch_bounds(256,8) -> 32 waves/CU possible. Half the per-block
// critical path of R6, 2x the independent pipelines per CU.
// Garbage rows 50..63: gathers never write them, h1 there is garbage (row-
// independent MFMA, discarded), out-partials live in rows 50..57 (fully dead).
__global__ __launch_bounds__(256, 8) void va_agg_kernel(
    const int*    __restrict__ nodes,
    const int*    __restrict__ hva,
    const int*    __restrict__ haf,
    const float*  __restrict__ v2e,
    const float*  __restrict__ a2e,
    const float*  __restrict__ f2e,
    const __bf16* __restrict__ wf,
    const float*  __restrict__ wsc,
    float*        __restrict__ out)
{
    __shared__ __bf16 xs[MR * XSS];   // 17408 B: [row][e_va 0..63 | e_af->h1 64..127]
    __shared__ float  pbuf[4 * MR];   // 1024 B : per-wave score partials

    const int tid  = threadIdx.x;
    const int w    = tid >> 6;
    const int lane = tid & 63;
    const int lq   = lane & 15;
    const int quad = lane >> 4;
    const int col  = w * 16 + lq;
    const int node = blockIdx.x;

    // ---- gathers FIRST: 100 rows x 16 float4 chunks (independent VMEM) ----
    {
        const int* hb = hva + node * HL;
        const int* fb = haf + node * HL;
        #pragma unroll
        for (int i = 0; i < 7; ++i) {
            int t = i * 256 + tid;
            if (t < HL * 2 * 16) {
                int r = t >> 4, q = t & 15;
                bool va = (r < HL);
                int gr = va ? r : r - HL;
                int idx = va ? hb[gr] : fb[gr];
                const float* src = (va ? a2e : f2e) + (size_t)idx * DD + q * 4;
                float4 v = *(const float4*)src;
                bf16x4 pk = {(__bf16)v.x, (__bf16)v.y, (__bf16)v.z, (__bf16)v.w};
                *(bf16x4*)&xs[gr * XSS + (va ? 0 : DD) + q * 4] = pk;
            }
        }
    }

    // ---- rep A-fragment (row 0 only; lanes lq==0) ----
    bf16x8 repf[2];
    #pragma unroll
    for (int t = 0; t < 2; ++t)
        #pragma unroll
        for (int j = 0; j < 8; ++j) repf[t][j] = (__bf16)0.f;
    if (lq == 0) {
        int nd = nodes[node];
        const float* rp = v2e + (size_t)nd * DD;
        #pragma unroll
        for (int t = 0; t < 2; ++t) {
            float4 v0 = *(const float4*)(rp + t * 32 + quad * 8);
            float4 v1 = *(const float4*)(rp + t * 32 + quad * 8 + 4);
            repf[t] = (bf16x8){(__bf16)v0.x, (__bf16)v0.y, (__bf16)v0.z, (__bf16)v0.w,
                               (__bf16)v1.x, (__bf16)v1.y, (__bf16)v1.z, (__bf16)v1.w};
        }
    }

    // ---- weight fragments: straight vector loads from prep-packed ws ----
    const __bf16* fbp = wf + (size_t)(quad * 64 + col) * 64;
    bf16x8 b1f[4], b1u[2], b2f[2];
    #pragma unroll
    for (int t = 0; t < 4; ++t) b1f[t] = *(const bf16x8*)(fbp + t * 8);
    #pragma unroll
    for (int t = 0; t < 2; ++t) {
        b1u[t] = *(const bf16x8*)(fbp + 32 + t * 8);
        b2f[t] = *(const bf16x8*)(fbp + 48 + t * 8);
    }
    const float w3c = wsc[col];
    const float b1c = wsc[64 + col];
    const float b2c = wsc[128 + col];

    // ---- bias MFMA: row0 = rep . W1[64:128, col] ----
    f32x4 rb = {0.f, 0.f, 0.f, 0.f};
    #pragma unroll
    for (int t = 0; t < 2; ++t)
        rb = __builtin_amdgcn_mfma_f32_16x16x32_bf16(repf[t], b1u[t], rb, 0, 0, 0);
    const float bias0 = __shfl(rb[0], lq) + b1c;   // C row 0: quad 0, reg 0, col=lq

    __syncthreads();   // [1] gathers visible

    // ---- GEMM1: h1 = relu(x @ W1eff + bias), M=64, K=128 ----
    f32x4 acc[MT];
    #pragma unroll
    for (int mt = 0; mt < MT; ++mt) acc[mt] = (f32x4){bias0, bias0, bias0, bias0};
    #pragma unroll
    for (int t = 0; t < 4; ++t)
        #pragma unroll
        for (int mt = 0; mt < MT; ++mt) {
            bf16x8 a = *(const bf16x8*)&xs[(mt * 16 + lq) * XSS + t * 32 + quad * 8];
            acc[mt] = __builtin_amdgcn_mfma_f32_16x16x32_bf16(a, b1f[t], acc[mt], 0, 0, 0);
        }
    __syncthreads();   // [2] e_af reads done before overwrite
    #pragma unroll
    for (int mt = 0; mt < MT; ++mt)
        #pragma unroll
        for (int r = 0; r < 4; ++r) {
            int gr = mt * 16 + quad * 4 + r;
            xs[gr * XSS + DD + col] = (__bf16)fmaxf(acc[mt][r], 0.f);
        }
    __syncthreads();   // [3] h1 visible

    // ---- GEMM2 + scores ----
    f32x4 a2[MT];
    #pragma unroll
    for (int mt = 0; mt < MT; ++mt) a2[mt] = (f32x4){b2c, b2c, b2c, b2c};
    #pragma unroll
    for (int t = 0; t < 2; ++t)
        #pragma unroll
        for (int mt = 0; mt < MT; ++mt) {
            bf16x8 a = *(const bf16x8*)&xs[(mt * 16 + lq) * XSS + DD + t * 32 + quad * 8];
            a2[mt] = __builtin_amdgcn_mfma_f32_16x16x32_bf16(a, b2f[t], a2[mt], 0, 0, 0);
        }
    #pragma unroll
    for (int mt = 0; mt < MT; ++mt) {
        float p0 = fmaxf(a2[mt][0], 0.f) * w3c;
        float p1 = fmaxf(a2[mt][1], 0.f) * w3c;
        float p2 = fmaxf(a2[mt][2], 0.f) * w3c;
        float p3 = fmaxf(a2[mt][3], 0.f) * w3c;
        #pragma unroll
        for (int m = 1; m < 16; m <<= 1) {
            p0 += __shfl_xor(p0, m);
            p1 += __shfl_xor(p1, m);
            p2 += __shfl_xor(p2, m);
            p3 += __shfl_xor(p3, m);
        }
        if (lq == 0) {
            int rowb = mt * 16 + quad * 4;
            pbuf[w * MR + rowb + 0] = p0;
            pbuf[w * MR + rowb + 1] = p1;
            pbuf[w * MR + rowb + 2] = p2;
            pbuf[w * MR + rowb + 3] = p3;
        }
    }
    __syncthreads();   // [4] scores visible

    // ---- softmax (all 4 waves redundantly, same node); b3 cancels ----
    float att;
    {
        float s = -3.0e38f;
        if (lane < HL)
            s = pbuf[lane] + pbuf[MR + lane] + pbuf[2 * MR + lane] + pbuf[3 * MR + lane];
        float mx = s;
        #pragma unroll
        for (int m = 1; m < 64; m <<= 1) mx = fmaxf(mx, __shfl_xor(mx, m));
        float e = (lane < HL) ? __expf(s - mx) : 0.f;
        float sm = e;
        #pragma unroll
        for (int m = 1; m < 64; m <<= 1) sm += __shfl_xor(sm, m);
        att = e / sm;
    }

    // ---- weighted e_va sum (l strided by wave); partials in dead rows 50..57 ----
    {
        float o = 0.f;
        #pragma unroll
        for (int i = 0; i < 13; ++i) {
            int l = w + 4 * i;
            if (l < HL) {
                float av = __shfl(att, l);
                o = fmaf(av, (float)xs[l * XSS + lane], o);
            }
        }
        float* op = (float*)&xs[(50 + 2 * w) * XSS];   // 256 B within rows 50+2w,51+2w
        op[lane] = o;
    }
    __syncthreads();   // [5] partials visible
    if (w == 0) {
        float o = 0.f;
        #pragma unroll
        for (int k = 0; k < 4; ++k)
            o += ((const float*)&xs[(50 + 2 * k) * XSS])[lane];
        out[(size_t)node * DD + lane] = o;
    }
}

extern "C" void kernel_launch(void* const* d_in, const int* in_sizes, int n_in,
                              void* d_out, int out_size, void* d_ws, size_t ws_size,
                              hipStream_t stream) {
    const int*   nodes = (const int*)d_in[0];
    const int*   hva   = (const int*)d_in[1];
    const int*   haf   = (const int*)d_in[2];
    const float* v2e   = (const float*)d_in[3];
    const float* a2e   = (const float*)d_in[4];
    const float* f2e   = (const float*)d_in[5];
    const float* W1    = (const float*)d_in[6];
    const float* b1    = (const float*)d_in[7];
    const float* W2    = (const float*)d_in[8];
    const float* b2    = (const float*)d_in[9];
    const float* w3    = (const float*)d_in[10];
    // d_in[11] = b3: softmax shift-invariant — unused.
    float* out = (float*)d_out;

    __bf16* wf  = (__bf16*)d_ws;                        // 32768 B fragments
    float*  wsc = (float*)((char*)d_ws + 256 * 64 * 2); // 768 B scalars

    va_prep_kernel<<<1, 256, 0, stream>>>(W1, W2, w3, b1, b2, wf, wsc);

    const int N = in_sizes[0];            // 8192
    va_agg_kernel<<<N, 256, 0, stream>>>(nodes, hva, haf, v2e, a2e, f2e,
                                         wf, wsc, out);
}

// Round 8
// 164.685 us; speedup vs baseline: 1.0390x; 1.0390x over previous
//
#include <hip/hip_runtime.h>
#include <hip/hip_bf16.h>

typedef __bf16 bf16x8 __attribute__((ext_vector_type(8)));
typedef __bf16 bf16x4 __attribute__((ext_vector_type(4)));
typedef float  f32x4  __attribute__((ext_vector_type(4)));

#define HL 50
#define DD 64

// ============================ NEW ALGORITHM =============================
// h1 = relu(A2[va] + F2[af] + ba[node]) where A2 = a2e@W1[0:64],
// F2 = f2e@W1[128:192] (bf16 tables, 12.8 MB each), ba = b1 + rep@W1[64:128].
// Main kernel: gather-2x16B -> h1 frag in regs -> GEMM2 (MFMA) -> scores ->
// softmax -> weighted sum of f32 e_va rows. No GEMM1, 1.3 KB LDS, 2 barriers.

// --- prep: dst[r][c] = bf16( sum_k src[r][k] * W1part[k][c] ), 64 rows/block
__global__ __launch_bounds__(256, 4) void prep_embed_kernel(
    const float* __restrict__ src, const float* __restrict__ W1part,
    __bf16* __restrict__ dst, int nrows)
{
    __shared__ __align__(16) __bf16 es[64 * 72];   // 9216 B
    const int tid = threadIdx.x;
    const int w = tid >> 6, lane = tid & 63, lq = lane & 15, quad = lane >> 4;
    const int col = w * 16 + lq;
    const int r0 = blockIdx.x * 64;

    #pragma unroll
    for (int i = 0; i < 4; ++i) {                  // stage 64 rows f32->bf16
        int t = i * 256 + tid;
        int row = t >> 4, q = t & 15;
        int gr = r0 + row; if (gr >= nrows) gr = nrows - 1;
        float4 v = *(const float4*)(src + (size_t)gr * DD + q * 4);
        bf16x4 pk = {(__bf16)v.x, (__bf16)v.y, (__bf16)v.z, (__bf16)v.w};
        *(bf16x4*)&es[row * 72 + q * 4] = pk;
    }
    bf16x8 bfr[2];
    #pragma unroll
    for (int t = 0; t < 2; ++t)
        #pragma unroll
        for (int j = 0; j < 8; ++j)
            bfr[t][j] = (__bf16)W1part[(t * 32 + quad * 8 + j) * DD + col];
    __syncthreads();

    f32x4 acc[4];
    #pragma unroll
    for (int mt = 0; mt < 4; ++mt) acc[mt] = (f32x4){0.f, 0.f, 0.f, 0.f};
    #pragma unroll
    for (int t = 0; t < 2; ++t)
        #pragma unroll
        for (int mt = 0; mt < 4; ++mt) {
            bf16x8 a = *(const bf16x8*)&es[(mt * 16 + lq) * 72 + t * 32 + quad * 8];
            acc[mt] = __builtin_amdgcn_mfma_f32_16x16x32_bf16(a, bfr[t], acc[mt], 0, 0, 0);
        }
    __syncthreads();
    #pragma unroll
    for (int mt = 0; mt < 4; ++mt)
        #pragma unroll
        for (int r = 0; r < 4; ++r)
            es[(mt * 16 + quad * 4 + r) * 72 + col] = (__bf16)acc[mt][r];
    __syncthreads();
    {   // coalesced 16B stores
        int row = tid >> 2, seg = tid & 3;
        int gr = r0 + row;
        if (gr < nrows) {
            bf16x8 vv = *(const bf16x8*)&es[row * 72 + seg * 16];
            *(bf16x8*)(dst + (size_t)gr * DD + seg * 16) = vv;
        }
    }
}

// --- prep: ba[n][c] = b1[c] + sum_k v2e[nodes[n]][k] * W1[64+k][c]
__global__ __launch_bounds__(256, 4) void prep_bias_kernel(
    const int* __restrict__ nodes, const float* __restrict__ v2e,
    const float* __restrict__ W1, const float* __restrict__ b1,
    float* __restrict__ ba, int N)
{
    __shared__ __align__(16) __bf16 rs[64 * 72];
    const int tid = threadIdx.x;
    const int w = tid >> 6, lane = tid & 63, lq = lane & 15, quad = lane >> 4;
    const int col = w * 16 + lq;
    const int n0 = blockIdx.x * 64;

    #pragma unroll
    for (int i = 0; i < 4; ++i) {
        int t = i * 256 + tid;
        int row = t >> 4, q = t & 15;
        int gn = n0 + row; if (gn >= N) gn = N - 1;
        int idx = nodes[gn];
        float4 v = *(const float4*)(v2e + (size_t)idx * DD + q * 4);
        bf16x4 pk = {(__bf16)v.x, (__bf16)v.y, (__bf16)v.z, (__bf16)v.w};
        *(bf16x4*)&rs[row * 72 + q * 4] = pk;
    }
    bf16x8 bfr[2];
    #pragma unroll
    for (int t = 0; t < 2; ++t)
        #pragma unroll
        for (int j = 0; j < 8; ++j)
            bfr[t][j] = (__bf16)W1[(64 + t * 32 + quad * 8 + j) * DD + col];
    const float b1c = b1[col];
    __syncthreads();

    f32x4 acc[4];
    #pragma unroll
    for (int mt = 0; mt < 4; ++mt) acc[mt] = (f32x4){0.f, 0.f, 0.f, 0.f};
    #pragma unroll
    for (int t = 0; t < 2; ++t)
        #pragma unroll
        for (int mt = 0; mt < 4; ++mt) {
            bf16x8 a = *(const bf16x8*)&rs[(mt * 16 + lq) * 72 + t * 32 + quad * 8];
            acc[mt] = __builtin_amdgcn_mfma_f32_16x16x32_bf16(a, bfr[t], acc[mt], 0, 0, 0);
        }
    #pragma unroll
    for (int mt = 0; mt < 4; ++mt)
        #pragma unroll
        for (int r = 0; r < 4; ++r) {
            int gn = n0 + mt * 16 + quad * 4 + r;
            if (gn < N) ba[(size_t)gn * DD + col] = acc[mt][r] + b1c;
        }
}

// --- prep: W2 B-fragments (lane ln holds W2[t*32+(ln>>4)*8+j][ct*16+(ln&15)])
//     wsc: [0..63] w3, [64..127] b2
__global__ __launch_bounds__(256) void prep_frag_kernel(
    const float* __restrict__ W2, const float* __restrict__ w3,
    const float* __restrict__ b2,
    __bf16* __restrict__ w2f, float* __restrict__ wsc)
{
    const int tid = threadIdx.x;
    const int ln = tid & 63, c0 = tid >> 6;
    #pragma unroll
    for (int h = 0; h < 2; ++h) {
        int combo = c0 + 4 * h;            // = ct*2 + t
        int ct = combo >> 1, t = combo & 1;
        __bf16* d = w2f + ((size_t)combo * 64 + ln) * 8;
        #pragma unroll
        for (int j = 0; j < 8; ++j)
            d[j] = (__bf16)W2[(t * 32 + (ln >> 4) * 8 + j) * DD + ct * 16 + (ln & 15)];
    }
    if (tid < 64) { wsc[tid] = w3[tid]; wsc[64 + tid] = b2[tid]; }
}

// --- main: one node per block
__global__ __launch_bounds__(256, 8) void va_main_kernel(
    const int*    __restrict__ hva,
    const int*    __restrict__ haf,
    const __bf16* __restrict__ A2,
    const __bf16* __restrict__ F2,
    const float*  __restrict__ eva,    // raw a2e f32 (output path)
    const float*  __restrict__ ba,
    const __bf16* __restrict__ w2f,
    const float*  __restrict__ wsc,
    float*        __restrict__ out)
{
    __shared__ float pbuf[64];
    __shared__ float ps[4 * 64];

    const int tid  = threadIdx.x;
    const int w    = tid >> 6;
    const int lane = tid & 63;
    const int lq   = lane & 15;
    const int quad = lane >> 4;
    const int node = blockIdx.x;
    const int* hb = hva + node * HL;
    const int* fb = haf + node * HL;

    // ---- gather h1 ingredients (2x16B per table per lane), issue first ----
    const int lr = min(w * 16 + lq, HL - 1);       // rows >=50 clamped (scores masked)
    const int ia = hb[lr];
    const int ifm = fb[lr];
    bf16x8 a2g[2], f2g[2];
    f32x4  bb[4];
    #pragma unroll
    for (int t = 0; t < 2; ++t) {
        a2g[t] = *(const bf16x8*)(A2 + (size_t)ia  * DD + t * 32 + quad * 8);
        f2g[t] = *(const bf16x8*)(F2 + (size_t)ifm * DD + t * 32 + quad * 8);
        bb[t * 2]     = *(const f32x4*)(ba + (size_t)node * DD + t * 32 + quad * 8);
        bb[t * 2 + 1] = *(const f32x4*)(ba + (size_t)node * DD + t * 32 + quad * 8 + 4);
    }

    // ---- h1 A-fragment: relu(A2g + F2g + bias), A[m=lq][k=quad*8+j] ----
    bf16x8 h1f[2];
    #pragma unroll
    for (int t = 0; t < 2; ++t)
        #pragma unroll
        for (int j = 0; j < 8; ++j) {
            float f = (float)a2g[t][j] + (float)f2g[t][j] + bb[t * 2 + (j >> 2)][j & 3];
            h1f[t][j] = (__bf16)fmaxf(f, 0.f);
        }

    // ---- GEMM2 (4 col-tiles x 2 K-steps) + score partials ----
    float srow[4] = {0.f, 0.f, 0.f, 0.f};
    #pragma unroll
    for (int ct = 0; ct < 4; ++ct) {
        const float b2c = wsc[64 + ct * 16 + lq];
        f32x4 acc = {b2c, b2c, b2c, b2c};
        #pragma unroll
        for (int t = 0; t < 2; ++t) {
            bf16x8 bfr = *(const bf16x8*)(w2f + ((size_t)(ct * 2 + t) * 64 + lane) * 8);
            acc = __builtin_amdgcn_mfma_f32_16x16x32_bf16(h1f[t], bfr, acc, 0, 0, 0);
        }
        const float w3c = wsc[ct * 16 + lq];
        #pragma unroll
        for (int r = 0; r < 4; ++r)
            srow[r] = fmaf(fmaxf(acc[r], 0.f), w3c, srow[r]);
    }
    #pragma unroll
    for (int r = 0; r < 4; ++r) {
        #pragma unroll
        for (int m = 1; m < 16; m <<= 1) srow[r] += __shfl_xor(srow[r], m);
    }
    if (lq == 0) {
        #pragma unroll
        for (int r = 0; r < 4; ++r) pbuf[w * 16 + quad * 4 + r] = srow[r];
    }

    // ---- prefetch output gathers (independent of barrier/softmax) ----
    int   oidx[13];
    float ev[13];
    #pragma unroll
    for (int i = 0; i < 13; ++i) {
        int l = w + 4 * i;
        oidx[i] = hb[(l < HL) ? l : 0];
    }
    #pragma unroll
    for (int i = 0; i < 13; ++i)
        ev[i] = eva[(size_t)oidx[i] * DD + lane];
    __syncthreads();   // [1] scores visible

    // ---- softmax over l (redundant per wave); b3 cancels ----
    float att;
    {
        float s = (lane < HL) ? pbuf[lane] : -3.0e38f;
        float mx = s;
        #pragma unroll
        for (int m = 1; m < 64; m <<= 1) mx = fmaxf(mx, __shfl_xor(mx, m));
        float e = (lane < HL) ? __expf(s - mx) : 0.f;
        float sm = e;
        #pragma unroll
        for (int m = 1; m < 64; m <<= 1) sm += __shfl_xor(sm, m);
        att = e / sm;
    }

    // ---- weighted e_va sum (f32), l strided by wave ----
    float o = 0.f;
    #pragma unroll
    for (int i = 0; i < 13; ++i) {
        int l = w + 4 * i;
        if (l < HL) {
            float av = __shfl(att, l);
            o = fmaf(av, ev[i], o);
        }
    }
    ps[w * 64 + lane] = o;
    __syncthreads();   // [2]
    if (w == 0)
        out[(size_t)node * DD + lane] =
            ps[lane] + ps[64 + lane] + ps[128 + lane] + ps[192 + lane];
}

// ======================= FALLBACK (proven R6 path) ======================
#define FMR  112
#define FMT  7
#define FXSS 136

__global__ __launch_bounds__(256) void fb_prep_kernel(
    const float* __restrict__ W1, const float* __restrict__ W2,
    const float* __restrict__ w3, const float* __restrict__ b1,
    const float* __restrict__ b2,
    __bf16* __restrict__ wf, float* __restrict__ wsc)
{
    const int tid  = threadIdx.x;
    const int quad = tid >> 6;
    const int col  = tid & 63;
    __bf16* dst = wf + tid * 64;
    #pragma unroll
    for (int t = 0; t < 4; ++t)
        #pragma unroll
        for (int j = 0; j < 8; ++j) {
            int keff = t * 32 + quad * 8 + j;
            int krow = (keff < 64) ? keff : keff + 64;
            dst[t * 8 + j] = (__bf16)W1[krow * 64 + col];
        }
    #pragma unroll
    for (int t = 0; t < 2; ++t)
        #pragma unroll
        for (int j = 0; j < 8; ++j) {
            dst[32 + t * 8 + j] = (__bf16)W1[(64 + t * 32 + quad * 8 + j) * 64 + col];
            dst[48 + t * 8 + j] = (__bf16)W2[(t * 32 + quad * 8 + j) * 64 + col];
        }
    if (tid < 64) {
        wsc[tid] = w3[tid]; wsc[64 + tid] = b1[tid]; wsc[128 + tid] = b2[tid];
    }
}

__global__ __launch_bounds__(256, 5) void fb_agg_kernel(
    const int* __restrict__ nodes, const int* __restrict__ hva,
    const int* __restrict__ haf, const float* __restrict__ v2e,
    const float* __restrict__ a2e, const float* __restrict__ f2e,
    const __bf16* __restrict__ wf, const float* __restrict__ wsc,
    float* __restrict__ out)
{
    __shared__ __bf16 xs[FMR * FXSS];
    __shared__ float  pbuf[4 * FMR];
    const int tid = threadIdx.x;
    const int w = tid >> 6, lane = tid & 63, lq = lane & 15, quad = lane >> 4;
    const int col = w * 16 + lq;
    const int n0 = blockIdx.x * 2;
    {
        const int* hb = hva + n0 * HL;
        const int* fb = haf + n0 * HL;
        #pragma unroll
        for (int i = 0; i < 13; ++i) {
            int t = i * 256 + tid;
            if (t < 2 * HL * 2 * 16) {
                int r = t >> 4, q = t & 15;
                bool va = (r < 2 * HL);
                int gr = va ? r : r - 2 * HL;
                int idx = va ? hb[gr] : fb[gr];
                const float* src = (va ? a2e : f2e) + (size_t)idx * DD + q * 4;
                float4 v = *(const float4*)src;
                bf16x4 pk = {(__bf16)v.x, (__bf16)v.y, (__bf16)v.z, (__bf16)v.w};
                *(bf16x4*)&xs[gr * FXSS + (va ? 0 : DD) + q * 4] = pk;
            }
        }
    }
    bf16x8 repf[2];
    #pragma unroll
    for (int t = 0; t < 2; ++t)
        #pragma unroll
        for (int j = 0; j < 8; ++j) repf[t][j] = (__bf16)0.f;
    if (lq < 2) {
        int nd = nodes[n0 + lq];
        const float* rp = v2e + (size_t)nd * DD;
        #pragma unroll
        for (int t = 0; t < 2; ++t) {
            float4 v0 = *(const float4*)(rp + t * 32 + quad * 8);
            float4 v1 = *(const float4*)(rp + t * 32 + quad * 8 + 4);
            repf[t] = (bf16x8){(__bf16)v0.x, (__bf16)v0.y, (__bf16)v0.z, (__bf16)v0.w,
                               (__bf16)v1.x, (__bf16)v1.y, (__bf16)v1.z, (__bf16)v1.w};
        }
    }
    const __bf16* fbp = wf + (size_t)(quad * 64 + col) * 64;
    bf16x8 b1f[4], b1u[2], b2f[2];
    #pragma unroll
    for (int t = 0; t < 4; ++t) b1f[t] = *(const bf16x8*)(fbp + t * 8);
    #pragma unroll
    for (int t = 0; t < 2; ++t) {
        b1u[t] = *(const bf16x8*)(fbp + 32 + t * 8);
        b2f[t] = *(const bf16x8*)(fbp + 48 + t * 8);
    }
    const float w3c = wsc[col];
    const float b1c = wsc[64 + col];
    const float b2c = wsc[128 + col];
    f32x4 rb = {0.f, 0.f, 0.f, 0.f};
    #pragma unroll
    for (int t = 0; t < 2; ++t)
        rb = __builtin_amdgcn_mfma_f32_16x16x32_bf16(repf[t], b1u[t], rb, 0, 0, 0);
    const float bias0 = __shfl(rb[0], lq) + b1c;
    const float bias1 = __shfl(rb[1], lq) + b1c;
    __syncthreads();
    f32x4 acc[FMT];
    #pragma unroll
    for (int mt = 0; mt < FMT; ++mt)
        #pragma unroll
        for (int r = 0; r < 4; ++r) {
            int gr = mt * 16 + quad * 4 + r;
            acc[mt][r] = (gr >= HL) ? bias1 : bias0;
        }
    #pragma unroll
    for (int t = 0; t < 4; ++t)
        #pragma unroll
        for (int mt = 0; mt < FMT; ++mt) {
            bf16x8 a = *(const bf16x8*)&xs[(mt * 16 + lq) * FXSS + t * 32 + quad * 8];
            acc[mt] = __builtin_amdgcn_mfma_f32_16x16x32_bf16(a, b1f[t], acc[mt], 0, 0, 0);
        }
    __syncthreads();
    #pragma unroll
    for (int mt = 0; mt < FMT; ++mt)
        #pragma unroll
        for (int r = 0; r < 4; ++r) {
            int gr = mt * 16 + quad * 4 + r;
            xs[gr * FXSS + DD + col] = (__bf16)fmaxf(acc[mt][r], 0.f);
        }
    __syncthreads();
    f32x4 a2[FMT];
    #pragma unroll
    for (int mt = 0; mt < FMT; ++mt) a2[mt] = (f32x4){b2c, b2c, b2c, b2c};
    #pragma unroll
    for (int t = 0; t < 2; ++t)
        #pragma unroll
        for (int mt = 0; mt < FMT; ++mt) {
            bf16x8 a = *(const bf16x8*)&xs[(mt * 16 + lq) * FXSS + DD + t * 32 + quad * 8];
            a2[mt] = __builtin_amdgcn_mfma_f32_16x16x32_bf16(a, b2f[t], a2[mt], 0, 0, 0);
        }
    #pragma unroll
    for (int mt = 0; mt < FMT; ++mt) {
        float p0 = fmaxf(a2[mt][0], 0.f) * w3c;
        float p1 = fmaxf(a2[mt][1], 0.f) * w3c;
        float p2 = fmaxf(a2[mt][2], 0.f) * w3c;
        float p3 = fmaxf(a2[mt][3], 0.f) * w3c;
        #pragma unroll
        for (int m = 1; m < 16; m <<= 1) {
            p0 += __shfl_xor(p0, m); p1 += __shfl_xor(p1, m);
            p2 += __shfl_xor(p2, m); p3 += __shfl_xor(p3, m);
        }
        if (lq == 0) {
            int rowb = mt * 16 + quad * 4;
            pbuf[w * FMR + rowb + 0] = p0; pbuf[w * FMR + rowb + 1] = p1;
            pbuf[w * FMR + rowb + 2] = p2; pbuf[w * FMR + rowb + 3] = p3;
        }
    }
    __syncthreads();
    const int n = w & 1, lh = w >> 1;
    float att;
    {
        float s = -3.0e38f;
        if (lane < HL) {
            int gr = n * HL + lane;
            s = pbuf[gr] + pbuf[FMR + gr] + pbuf[2 * FMR + gr] + pbuf[3 * FMR + gr];
        }
        float mx = s;
        #pragma unroll
        for (int m = 1; m < 64; m <<= 1) mx = fmaxf(mx, __shfl_xor(mx, m));
        float e = (lane < HL) ? __expf(s - mx) : 0.f;
        float sm = e;
        #pragma unroll
        for (int m = 1; m < 64; m <<= 1) sm += __shfl_xor(sm, m);
        att = e / sm;
    }
    {
        float o = 0.f;
        const int lb = lh * 25;
        #pragma unroll
        for (int i = 0; i < 25; ++i) {
            int l = lb + i;
            float av = __shfl(att, l);
            o = fmaf(av, (float)xs[(n * HL + l) * FXSS + lane], o);
        }
        float* op = (float*)&xs[(100 + w) * FXSS + DD];
        op[lane] = o;
    }
    __syncthreads();
    if (w < 2) {
        const float* p0 = (const float*)&xs[(100 + w) * FXSS + DD];
        const float* p1 = (const float*)&xs[(100 + w + 2) * FXSS + DD];
        out[(size_t)(n0 + w) * DD + lane] = p0[lane] + p1[lane];
    }
}

// ================================ host ==================================
extern "C" void kernel_launch(void* const* d_in, const int* in_sizes, int n_in,
                              void* d_out, int out_size, void* d_ws, size_t ws_size,
                              hipStream_t stream) {
    const int*   nodes = (const int*)d_in[0];
    const int*   hva   = (const int*)d_in[1];
    const int*   haf   = (const int*)d_in[2];
    const float* v2e   = (const float*)d_in[3];
    const float* a2e   = (const float*)d_in[4];
    const float* f2e   = (const float*)d_in[5];
    const float* W1    = (const float*)d_in[6];
    const float* b1    = (const float*)d_in[7];
    const float* W2    = (const float*)d_in[8];
    const float* b2    = (const float*)d_in[9];
    const float* w3    = (const float*)d_in[10];
    // d_in[11] = b3: softmax shift-invariant — unused.
    float* out = (float*)d_out;

    const int N  = in_sizes[0];            // 8192
    const int nA = in_sizes[4] / DD;       // 100000
    const int nF = in_sizes[5] / DD;       // 100000

    size_t offA2 = 0;
    size_t offF2 = (offA2 + (size_t)nA * DD * 2 + 255) & ~(size_t)255;
    size_t offBA = (offF2 + (size_t)nF * DD * 2 + 255) & ~(size_t)255;
    size_t offWF = (offBA + (size_t)N * DD * 4 + 255) & ~(size_t)255;
    size_t offSC = offWF + 8 * 64 * 8 * 2;
    size_t need  = offSC + 128 * 4;

    if (ws_size >= need) {
        __bf16* A2  = (__bf16*)((char*)d_ws + offA2);
        __bf16* F2  = (__bf16*)((char*)d_ws + offF2);
        float*  ba  = (float*)((char*)d_ws + offBA);
        __bf16* w2f = (__bf16*)((char*)d_ws + offWF);
        float*  wsc = (float*)((char*)d_ws + offSC);

        prep_frag_kernel<<<1, 256, 0, stream>>>(W2, w3, b2, w2f, wsc);
        prep_bias_kernel<<<(N + 63) / 64, 256, 0, stream>>>(nodes, v2e, W1, b1, ba, N);
        prep_embed_kernel<<<(nA + 63) / 64, 256, 0, stream>>>(a2e, W1, A2, nA);
        prep_embed_kernel<<<(nF + 63) / 64, 256, 0, stream>>>(f2e, W1 + 128 * DD, F2, nF);
        va_main_kernel<<<N, 256, 0, stream>>>(hva, haf, A2, F2, a2e, ba, w2f, wsc, out);
    } else {
        // workspace too small for precompute path — proven R6 fallback (33 KB)
        __bf16* wf  = (__bf16*)d_ws;
        float*  wsc = (float*)((char*)d_ws + 256 * 64 * 2);
        fb_prep_kernel<<<1, 256, 0, stream>>>(W1, W2, w3, b1, b2, wf, wsc);
        fb_agg_kernel<<<N / 2, 256, 0, stream>>>(nodes, hva, haf, v2e, a2e, f2e,
                                                 wf, wsc, out);
    }
}

// Round 9
// 160.013 us; speedup vs baseline: 1.0694x; 1.0292x over previous
//
#include <hip/hip_runtime.h>
#include <hip/hip_bf16.h>

typedef __bf16    bf16x8 __attribute__((ext_vector_type(8)));
typedef __bf16    bf16x4 __attribute__((ext_vector_type(4)));
typedef _Float16  f16x8  __attribute__((ext_vector_type(8)));
typedef _Float16  f16x4  __attribute__((ext_vector_type(4)));
typedef float     f32x4  __attribute__((ext_vector_type(4)));

#define HL 50
#define DD 64

// ============================ ALGORITHM =================================
// h1 = relu(A2[va] + F2[af] + ba[node]) with A2 = f16(a2e@W1[0:64]),
// F2 = f16(f2e@W1[128:192]), ba = f16(b1 + rep@W1[64:128]).  E16 = f16(a2e)
// feeds the output weighted sum.  All derived tables f16 (packed adds,
// tighter than the bf16 path validated at 1.22e-4 through R7).
// One fused prep dispatch builds everything; main kernel: 1 node/block,
// 2 barriers, 1.3 KB LDS.

// ---- fused prep: [0,GA) A2+E16 | [GA,GA+GF) F2 | bias | last block frags
__global__ __launch_bounds__(256, 4) void prep_all_kernel(
    const int*   __restrict__ nodes,
    const float* __restrict__ v2e,
    const float* __restrict__ a2e,
    const float* __restrict__ f2e,
    const float* __restrict__ W1,
    const float* __restrict__ b1,
    const float* __restrict__ W2,
    const float* __restrict__ b2,
    const float* __restrict__ w3,
    _Float16* __restrict__ A2, _Float16* __restrict__ F2,
    _Float16* __restrict__ E16, _Float16* __restrict__ ba16,
    _Float16* __restrict__ w2f, float* __restrict__ wsc,
    int nA, int nF, int N, int GA, int GF, int GB)
{
    __shared__ __align__(16) _Float16 es[64 * 72];   // 9216 B
    const int tid  = threadIdx.x;
    const int w    = tid >> 6, lane = tid & 63;
    const int lq   = lane & 15, quad = lane >> 4;
    const int col  = w * 16 + lq;
    const int bid  = blockIdx.x;

    if (bid < GA + GF) {
        // ---- embed transform branch: dst = f16(src @ W1part) ----
        const bool  isA   = (bid < GA);
        const int   rb    = isA ? bid : bid - GA;
        const int   nrows = isA ? nA : nF;
        const float* src  = isA ? a2e : f2e;
        const float* Wp   = isA ? W1 : (W1 + 128 * DD);
        _Float16*   dst   = isA ? A2 : F2;
        const int   r0    = rb * 64;

        #pragma unroll
        for (int i = 0; i < 4; ++i) {
            int t = i * 256 + tid;
            int row = t >> 4, q = t & 15;
            int gr = r0 + row; if (gr >= nrows) gr = nrows - 1;
            float4 v = *(const float4*)(src + (size_t)gr * DD + q * 4);
            f16x4 pk = {(_Float16)v.x, (_Float16)v.y, (_Float16)v.z, (_Float16)v.w};
            *(f16x4*)&es[row * 72 + q * 4] = pk;
            if (isA) *(f16x4*)(E16 + (size_t)gr * DD + q * 4) = pk;  // free f16 e_va copy
        }
        f16x8 bfr[2];
        #pragma unroll
        for (int t = 0; t < 2; ++t)
            #pragma unroll
            for (int j = 0; j < 8; ++j)
                bfr[t][j] = (_Float16)Wp[(t * 32 + quad * 8 + j) * DD + col];
        __syncthreads();

        f32x4 acc[4];
        #pragma unroll
        for (int mt = 0; mt < 4; ++mt) acc[mt] = (f32x4){0.f, 0.f, 0.f, 0.f};
        #pragma unroll
        for (int t = 0; t < 2; ++t)
            #pragma unroll
            for (int mt = 0; mt < 4; ++mt) {
                f16x8 a = *(const f16x8*)&es[(mt * 16 + lq) * 72 + t * 32 + quad * 8];
                acc[mt] = __builtin_amdgcn_mfma_f32_16x16x32_f16(a, bfr[t], acc[mt], 0, 0, 0);
            }
        __syncthreads();
        #pragma unroll
        for (int mt = 0; mt < 4; ++mt)
            #pragma unroll
            for (int r = 0; r < 4; ++r)
                es[(mt * 16 + quad * 4 + r) * 72 + col] = (_Float16)acc[mt][r];
        __syncthreads();
        {   // coalesced 16B stores
            int row = tid >> 2, seg = tid & 3;
            int gr = r0 + row;
            if (gr < nrows) {
                f16x8 vv = *(const f16x8*)&es[row * 72 + seg * 16];
                *(f16x8*)(dst + (size_t)gr * DD + seg * 16) = vv;
            }
        }
    } else if (bid < GA + GF + GB) {
        // ---- bias branch: ba16[n][c] = f16(b1[c] + rep_n . W1[64:128, c]) ----
        const int n0 = (bid - GA - GF) * 64;
        #pragma unroll
        for (int i = 0; i < 4; ++i) {
            int t = i * 256 + tid;
            int row = t >> 4, q = t & 15;
            int gn = n0 + row; if (gn >= N) gn = N - 1;
            int idx = nodes[gn];
            float4 v = *(const float4*)(v2e + (size_t)idx * DD + q * 4);
            f16x4 pk = {(_Float16)v.x, (_Float16)v.y, (_Float16)v.z, (_Float16)v.w};
            *(f16x4*)&es[row * 72 + q * 4] = pk;
        }
        f16x8 bfr[2];
        #pragma unroll
        for (int t = 0; t < 2; ++t)
            #pragma unroll
            for (int j = 0; j < 8; ++j)
                bfr[t][j] = (_Float16)W1[(64 + t * 32 + quad * 8 + j) * DD + col];
        const float b1c = b1[col];
        __syncthreads();

        f32x4 acc[4];
        #pragma unroll
        for (int mt = 0; mt < 4; ++mt) acc[mt] = (f32x4){0.f, 0.f, 0.f, 0.f};
        #pragma unroll
        for (int t = 0; t < 2; ++t)
            #pragma unroll
            for (int mt = 0; mt < 4; ++mt) {
                f16x8 a = *(const f16x8*)&es[(mt * 16 + lq) * 72 + t * 32 + quad * 8];
                acc[mt] = __builtin_amdgcn_mfma_f32_16x16x32_f16(a, bfr[t], acc[mt], 0, 0, 0);
            }
        #pragma unroll
        for (int mt = 0; mt < 4; ++mt)
            #pragma unroll
            for (int r = 0; r < 4; ++r) {
                int gn = n0 + mt * 16 + quad * 4 + r;
                if (gn < N) ba16[(size_t)gn * DD + col] = (_Float16)(acc[mt][r] + b1c);
            }
    } else {
        // ---- frag branch: W2 B-fragments (f16) + scalars ----
        const int ln = tid & 63, c0 = tid >> 6;
        #pragma unroll
        for (int h = 0; h < 2; ++h) {
            int combo = c0 + 4 * h;          // = ct*2 + t
            int ct = combo >> 1, t = combo & 1;
            _Float16* d = w2f + ((size_t)combo * 64 + ln) * 8;
            #pragma unroll
            for (int j = 0; j < 8; ++j)
                d[j] = (_Float16)W2[(t * 32 + (ln >> 4) * 8 + j) * DD + ct * 16 + (ln & 15)];
        }
        if (tid < 64) { wsc[tid] = w3[tid]; wsc[64 + tid] = b2[tid]; }
    }
}

// ---- main: one node per block, f16 tables, 2 barriers ----
__global__ __launch_bounds__(256, 8) void va_main_kernel(
    const int*      __restrict__ hva,
    const int*      __restrict__ haf,
    const _Float16* __restrict__ A2,
    const _Float16* __restrict__ F2,
    const _Float16* __restrict__ E16,
    const _Float16* __restrict__ ba16,
    const _Float16* __restrict__ w2f,
    const float*    __restrict__ wsc,
    float*          __restrict__ out)
{
    __shared__ float pbuf[64];
    __shared__ float ps[4 * 64];

    const int tid  = threadIdx.x;
    const int w    = tid >> 6;
    const int lane = tid & 63;
    const int lq   = lane & 15;
    const int quad = lane >> 4;
    const int node = blockIdx.x;
    const int* hb = hva + node * HL;
    const int* fb = haf + node * HL;

    // ---- h1 fragment gathers (valid rows only; rows >=50 contribute 0) ----
    const int  lr0   = w * 16 + lq;
    const bool valid = (lr0 < HL);
    f16x8 h1f[2];
    #pragma unroll
    for (int t = 0; t < 2; ++t)
        #pragma unroll
        for (int j = 0; j < 8; ++j) h1f[t][j] = (_Float16)0.f;
    if (valid) {
        const int ia  = hb[lr0];
        const int ifm = fb[lr0];
        f16x8 a2g[2], f2g[2], bag[2];
        #pragma unroll
        for (int t = 0; t < 2; ++t) {
            a2g[t] = *(const f16x8*)(A2   + (size_t)ia   * DD + t * 32 + quad * 8);
            f2g[t] = *(const f16x8*)(F2   + (size_t)ifm  * DD + t * 32 + quad * 8);
            bag[t] = *(const f16x8*)(ba16 + (size_t)node * DD + t * 32 + quad * 8);
        }
        #pragma unroll
        for (int t = 0; t < 2; ++t) {
            f16x8 h = a2g[t] + f2g[t] + bag[t];      // packed f16 adds
            #pragma unroll
            for (int j = 0; j < 8; ++j)
                h1f[t][j] = (h[j] > (_Float16)0.f) ? h[j] : (_Float16)0.f;
        }
    }

    // ---- GEMM2 (4 col-tiles x 2 K-steps) + score partials ----
    float srow[4] = {0.f, 0.f, 0.f, 0.f};
    #pragma unroll
    for (int ct = 0; ct < 4; ++ct) {
        const float b2c = wsc[64 + ct * 16 + lq];
        f32x4 acc = {b2c, b2c, b2c, b2c};
        #pragma unroll
        for (int t = 0; t < 2; ++t) {
            f16x8 bfr = *(const f16x8*)(w2f + ((size_t)(ct * 2 + t) * 64 + lane) * 8);
            acc = __builtin_amdgcn_mfma_f32_16x16x32_f16(h1f[t], bfr, acc, 0, 0, 0);
        }
        const float w3c = wsc[ct * 16 + lq];
        #pragma unroll
        for (int r = 0; r < 4; ++r)
            srow[r] = fmaf(fmaxf(acc[r], 0.f), w3c, srow[r]);
    }
    #pragma unroll
    for (int r = 0; r < 4; ++r) {
        #pragma unroll
        for (int m = 1; m < 16; m <<= 1) srow[r] += __shfl_xor(srow[r], m);
    }
    if (lq == 0) {
        #pragma unroll
        for (int r = 0; r < 4; ++r) pbuf[w * 16 + quad * 4 + r] = srow[r];
    }

    // ---- prefetch output gathers: 1 idx load + shfl broadcast ----
    const int iv = hb[(lane < HL) ? lane : 0];   // lane l holds hva[l]
    float ev[13];
    #pragma unroll
    for (int i = 0; i < 13; ++i) {
        int l = w + 4 * i;                       // wave-uniform
        if (l < HL) {
            int idx = __shfl(iv, l);
            ev[i] = (float)E16[(size_t)idx * DD + lane];
        }
    }
    __syncthreads();   // [1] scores visible

    // ---- softmax over l (redundant per wave); b3 cancels ----
    float att;
    {
        float s = (lane < HL) ? pbuf[lane] : -3.0e38f;
        float mx = s;
        #pragma unroll
        for (int m = 1; m < 64; m <<= 1) mx = fmaxf(mx, __shfl_xor(mx, m));
        float e = (lane < HL) ? __expf(s - mx) : 0.f;
        float sm = e;
        #pragma unroll
        for (int m = 1; m < 64; m <<= 1) sm += __shfl_xor(sm, m);
        att = e / sm;
    }

    // ---- weighted e_va sum, l strided by wave ----
    float o = 0.f;
    #pragma unroll
    for (int i = 0; i < 13; ++i) {
        int l = w + 4 * i;
        if (l < HL) {
            float av = __shfl(att, l);
            o = fmaf(av, ev[i], o);
        }
    }
    ps[w * 64 + lane] = o;
    __syncthreads();   // [2]
    if (w == 0)
        out[(size_t)node * DD + lane] =
            ps[lane] + ps[64 + lane] + ps[128 + lane] + ps[192 + lane];
}

// ======================= FALLBACK (proven R6 path) ======================
#define FMR  112
#define FMT  7
#define FXSS 136

__global__ __launch_bounds__(256) void fb_prep_kernel(
    const float* __restrict__ W1, const float* __restrict__ W2,
    const float* __restrict__ w3, const float* __restrict__ b1,
    const float* __restrict__ b2,
    __bf16* __restrict__ wf, float* __restrict__ wsc)
{
    const int tid  = threadIdx.x;
    const int quad = tid >> 6;
    const int col  = tid & 63;
    __bf16* dst = wf + tid * 64;
    #pragma unroll
    for (int t = 0; t < 4; ++t)
        #pragma unroll
        for (int j = 0; j < 8; ++j) {
            int keff = t * 32 + quad * 8 + j;
            int krow = (keff < 64) ? keff : keff + 64;
            dst[t * 8 + j] = (__bf16)W1[krow * 64 + col];
        }
    #pragma unroll
    for (int t = 0; t < 2; ++t)
        #pragma unroll
        for (int j = 0; j < 8; ++j) {
            dst[32 + t * 8 + j] = (__bf16)W1[(64 + t * 32 + quad * 8 + j) * 64 + col];
            dst[48 + t * 8 + j] = (__bf16)W2[(t * 32 + quad * 8 + j) * 64 + col];
        }
    if (tid < 64) {
        wsc[tid] = w3[tid]; wsc[64 + tid] = b1[tid]; wsc[128 + tid] = b2[tid];
    }
}

__global__ __launch_bounds__(256, 5) void fb_agg_kernel(
    const int* __restrict__ nodes, const int* __restrict__ hva,
    const int* __restrict__ haf, const float* __restrict__ v2e,
    const float* __restrict__ a2e, const float* __restrict__ f2e,
    const __bf16* __restrict__ wf, const float* __restrict__ wsc,
    float* __restrict__ out)
{
    __shared__ __bf16 xs[FMR * FXSS];
    __shared__ float  pbuf[4 * FMR];
    const int tid = threadIdx.x;
    const int w = tid >> 6, lane = tid & 63, lq = lane & 15, quad = lane >> 4;
    const int col = w * 16 + lq;
    const int n0 = blockIdx.x * 2;
    {
        const int* hb = hva + n0 * HL;
        const int* fb = haf + n0 * HL;
        #pragma unroll
        for (int i = 0; i < 13; ++i) {
            int t = i * 256 + tid;
            if (t < 2 * HL * 2 * 16) {
                int r = t >> 4, q = t & 15;
                bool va = (r < 2 * HL);
                int gr = va ? r : r - 2 * HL;
                int idx = va ? hb[gr] : fb[gr];
                const float* src = (va ? a2e : f2e) + (size_t)idx * DD + q * 4;
                float4 v = *(const float4*)src;
                bf16x4 pk = {(__bf16)v.x, (__bf16)v.y, (__bf16)v.z, (__bf16)v.w};
                *(bf16x4*)&xs[gr * FXSS + (va ? 0 : DD) + q * 4] = pk;
            }
        }
    }
    bf16x8 repf[2];
    #pragma unroll
    for (int t = 0; t < 2; ++t)
        #pragma unroll
        for (int j = 0; j < 8; ++j) repf[t][j] = (__bf16)0.f;
    if (lq < 2) {
        int nd = nodes[n0 + lq];
        const float* rp = v2e + (size_t)nd * DD;
        #pragma unroll
        for (int t = 0; t < 2; ++t) {
            float4 v0 = *(const float4*)(rp + t * 32 + quad * 8);
            float4 v1 = *(const float4*)(rp + t * 32 + quad * 8 + 4);
            repf[t] = (bf16x8){(__bf16)v0.x, (__bf16)v0.y, (__bf16)v0.z, (__bf16)v0.w,
                               (__bf16)v1.x, (__bf16)v1.y, (__bf16)v1.z, (__bf16)v1.w};
        }
    }
    const __bf16* fbp = wf + (size_t)(quad * 64 + col) * 64;
    bf16x8 b1f[4], b1u[2], b2f[2];
    #pragma unroll
    for (int t = 0; t < 4; ++t) b1f[t] = *(const bf16x8*)(fbp + t * 8);
    #pragma unroll
    for (int t = 0; t < 2; ++t) {
        b1u[t] = *(const bf16x8*)(fbp + 32 + t * 8);
        b2f[t] = *(const bf16x8*)(fbp + 48 + t * 8);
    }
    const float w3c = wsc[col];
    const float b1c = wsc[64 + col];
    const float b2c = wsc[128 + col];
    f32x4 rb = {0.f, 0.f, 0.f, 0.f};
    #pragma unroll
    for (int t = 0; t < 2; ++t)
        rb = __builtin_amdgcn_mfma_f32_16x16x32_bf16(repf[t], b1u[t], rb, 0, 0, 0);
    const float bias0 = __shfl(rb[0], lq) + b1c;
    const float bias1 = __shfl(rb[1], lq) + b1c;
    __syncthreads();
    f32x4 acc[FMT];
    #pragma unroll
    for (int mt = 0; mt < FMT; ++mt)
        #pragma unroll
        for (int r = 0; r < 4; ++r) {
            int gr = mt * 16 + quad * 4 + r;
            acc[mt][r] = (gr >= HL) ? bias1 : bias0;
        }
    #pragma unroll
    for (int t = 0; t < 4; ++t)
        #pragma unroll
        for (int mt = 0; mt < FMT; ++mt) {
            bf16x8 a = *(const bf16x8*)&xs[(mt * 16 + lq) * FXSS + t * 32 + quad * 8];
            acc[mt] = __builtin_amdgcn_mfma_f32_16x16x32_bf16(a, b1f[t], acc[mt], 0, 0, 0);
        }
    __syncthreads();
    #pragma unroll
    for (int mt = 0; mt < FMT; ++mt)
        #pragma unroll
        for (int r = 0; r < 4; ++r) {
            int gr = mt * 16 + quad * 4 + r;
            xs[gr * FXSS + DD + col] = (__bf16)fmaxf(acc[mt][r], 0.f);
        }
    __syncthreads();
    f32x4 a2[FMT];
    #pragma unroll
    for (int mt = 0; mt < FMT; ++mt) a2[mt] = (f32x4){b2c, b2c, b2c, b2c};
    #pragma unroll
    for (int t = 0; t < 2; ++t)
        #pragma unroll
        for (int mt = 0; mt < FMT; ++mt) {
            bf16x8 a = *(const bf16x8*)&xs[(mt * 16 + lq) * FXSS + DD + t * 32 + quad * 8];
            a2[mt] = __builtin_amdgcn_mfma_f32_16x16x32_bf16(a, b2f[t], a2[mt], 0, 0, 0);
        }
    #pragma unroll
    for (int mt = 0; mt < FMT; ++mt) {
        float p0 = fmaxf(a2[mt][0], 0.f) * w3c;
        float p1 = fmaxf(a2[mt][1], 0.f) * w3c;
        float p2 = fmaxf(a2[mt][2], 0.f) * w3c;
        float p3 = fmaxf(a2[mt][3], 0.f) * w3c;
        #pragma unroll
        for (int m = 1; m < 16; m <<= 1) {
            p0 += __shfl_xor(p0, m); p1 += __shfl_xor(p1, m);
            p2 += __shfl_xor(p2, m); p3 += __shfl_xor(p3, m);
        }
        if (lq == 0) {
            int rowb = mt * 16 + quad * 4;
            pbuf[w * FMR + rowb + 0] = p0; pbuf[w * FMR + rowb + 1] = p1;
            pbuf[w * FMR + rowb + 2] = p2; pbuf[w * FMR + rowb + 3] = p3;
        }
    }
    __syncthreads();
    const int n = w & 1, lh = w >> 1;
    float att;
    {
        float s = -3.0e38f;
        if (lane < HL) {
            int gr = n * HL + lane;
            s = pbuf[gr] + pbuf[FMR + gr] + pbuf[2 * FMR + gr] + pbuf[3 * FMR + gr];
        }
        float mx = s;
        #pragma unroll
        for (int m = 1; m < 64; m <<= 1) mx = fmaxf(mx, __shfl_xor(mx, m));
        float e = (lane < HL) ? __expf(s - mx) : 0.f;
        float sm = e;
        #pragma unroll
        for (int m = 1; m < 64; m <<= 1) sm += __shfl_xor(sm, m);
        att = e / sm;
    }
    {
        float o = 0.f;
        const int lb = lh * 25;
        #pragma unroll
        for (int i = 0; i < 25; ++i) {
            int l = lb + i;
            float av = __shfl(att, l);
            o = fmaf(av, (float)xs[(n * HL + l) * FXSS + lane], o);
        }
        float* op = (float*)&xs[(100 + w) * FXSS + DD];
        op[lane] = o;
    }
    __syncthreads();
    if (w < 2) {
        const float* p0 = (const float*)&xs[(100 + w) * FXSS + DD];
        const float* p1 = (const float*)&xs[(100 + w + 2) * FXSS + DD];
        out[(size_t)(n0 + w) * DD + lane] = p0[lane] + p1[lane];
    }
}

// ================================ host ==================================
extern "C" void kernel_launch(void* const* d_in, const int* in_sizes, int n_in,
                              void* d_out, int out_size, void* d_ws, size_t ws_size,
                              hipStream_t stream) {
    const int*   nodes = (const int*)d_in[0];
    const int*   hva   = (const int*)d_in[1];
    const int*   haf   = (const int*)d_in[2];
    const float* v2e   = (const float*)d_in[3];
    const float* a2e   = (const float*)d_in[4];
    const float* f2e   = (const float*)d_in[5];
    const float* W1    = (const float*)d_in[6];
    const float* b1    = (const float*)d_in[7];
    const float* W2    = (const float*)d_in[8];
    const float* b2    = (const float*)d_in[9];
    const float* w3    = (const float*)d_in[10];
    // d_in[11] = b3: softmax shift-invariant — unused.
    float* out = (float*)d_out;

    const int N  = in_sizes[0];            // 8192
    const int nA = in_sizes[4] / DD;       // 100000
    const int nF = in_sizes[5] / DD;       // 100000

    size_t offA2 = 0;
    size_t offF2 = (offA2 + (size_t)nA * DD * 2 + 255) & ~(size_t)255;
    size_t offE  = (offF2 + (size_t)nF * DD * 2 + 255) & ~(size_t)255;
    size_t offBA = (offE  + (size_t)nA * DD * 2 + 255) & ~(size_t)255;
    size_t offWF = (offBA + (size_t)N * DD * 2 + 255) & ~(size_t)255;
    size_t offSC = offWF + 8 * 64 * 8 * 2;
    size_t need  = offSC + 128 * 4;

    if (ws_size >= need) {
        _Float16* A2  = (_Float16*)((char*)d_ws + offA2);
        _Float16* F2  = (_Float16*)((char*)d_ws + offF2);
        _Float16* E16 = (_Float16*)((char*)d_ws + offE);
        _Float16* ba  = (_Float16*)((char*)d_ws + offBA);
        _Float16* w2f = (_Float16*)((char*)d_ws + offWF);
        float*    wsc = (float*)((char*)d_ws + offSC);

        const int GA = (nA + 63) / 64;
        const int GF = (nF + 63) / 64;
        const int GB = (N + 63) / 64;
        prep_all_kernel<<<GA + GF + GB + 1, 256, 0, stream>>>(
            nodes, v2e, a2e, f2e, W1, b1, W2, b2, w3,
            A2, F2, E16, ba, w2f, wsc, nA, nF, N, GA, GF, GB);
        va_main_kernel<<<N, 256, 0, stream>>>(hva, haf, A2, F2, E16, ba, w2f, wsc, out);
    } else {
        // workspace too small for precompute path — proven R6 fallback (33 KB)
        __bf16* wf  = (__bf16*)d_ws;
        float*  wsc = (float*)((char*)d_ws + 256 * 64 * 2);
        fb_prep_kernel<<<1, 256, 0, stream>>>(W1, W2, w3, b1, b2, wf, wsc);
        fb_agg_kernel<<<N / 2, 256, 0, stream>>>(nodes, hva, haf, v2e, a2e, f2e,
                                                 wf, wsc, out);
    }
}